// Round 3
// baseline (1792.821 us; speedup 1.0000x reference)
//
#include <hip/hip_runtime.h>
#include <hip/hip_bf16.h>
#include <cstdint>

// InterModalityUpdate — inputs/outputs are FLOAT32 (reference dtype); internal
// compute is bf16 MFMA with fp32 accumulation (2%-of-max threshold allows it).
//   v_trans = relu(v@Wv+bv)*v_mask ; q_trans = relu(q@Wq+bq)*q_mask
//   cross attention (q2v, v2q) with MFMA QK^T / PV, softmax in fp32
//   updated_v = relu([v|v_update]@Wvo+bvo) ; updated_q = relu([q|q_update]@Wqo+bqo)
// Dims fixed: B=16 N=M=512 VS=2048 QS=1024 OS=2048 H=16 DH=128.

typedef __hip_bfloat16 bf16;
typedef __attribute__((ext_vector_type(8))) __bf16 bf16x8;
typedef __attribute__((ext_vector_type(4))) float f32x4;
typedef __attribute__((ext_vector_type(4))) unsigned short us4;
typedef __attribute__((ext_vector_type(8))) unsigned short us8;

#define AS1 __attribute__((address_space(1)))
#define AS3 __attribute__((address_space(3)))

__device__ __forceinline__ void gl_lds16(const bf16* g, bf16* l) {
    // async global->LDS, 16B per lane; LDS dest = wave-uniform base + lane*16
    __builtin_amdgcn_global_load_lds((AS1 void*)(uintptr_t)(g), (AS3 void*)(l), 16, 0, 0);
}

__device__ __forceinline__ bf16x8 ld8(const bf16* p) { return *(const bf16x8*)p; }

__device__ __forceinline__ f32x4 mfma16(bf16x8 a, bf16x8 b, f32x4 c) {
    return __builtin_amdgcn_mfma_f32_16x16x32_bf16(a, b, c, 0, 0, 0);
}

// f32 -> bf16 bits, round-to-nearest-even (finite inputs)
__device__ __forceinline__ unsigned short f2bs(float f) {
    unsigned u = __builtin_bit_cast(unsigned, f);
    unsigned r = u + 0x7FFFu + ((u >> 16) & 1u);
    return (unsigned short)(r >> 16);
}

__device__ __forceinline__ void stout(bf16* p, float v) { *p = __float2bfloat16(v); }
__device__ __forceinline__ void stout(float* p, float v) { *p = v; }

// ---------------------------------------------------------------------------
// f32 -> bf16 convert, writing into the left columns of a wider bf16 matrix.
// 8 elems/thread. chunks-per-row = 1<<cprShift.
__global__ __launch_bounds__(256) void cvt_cols_k(
    const float* __restrict__ src, bf16* __restrict__ dst,
    int cprShift, int dstStride, int totalChunks)
{
    const int id = blockIdx.x * 256 + threadIdx.x;
    if (id >= totalChunks) return;
    const int row = id >> cprShift;
    const int cc = (id - (row << cprShift)) << 3;
    const float* s = src + ((size_t)row << (cprShift + 3)) + cc;
    const float4 a = *(const float4*)s;
    const float4 b = *(const float4*)(s + 4);
    us8 o;
    o[0] = f2bs(a.x); o[1] = f2bs(a.y); o[2] = f2bs(a.z); o[3] = f2bs(a.w);
    o[4] = f2bs(b.x); o[5] = f2bs(b.y); o[6] = f2bs(b.z); o[7] = f2bs(b.w);
    *(us8*)(dst + (size_t)row * dstStride + cc) = o;
}

// ---------------------------------------------------------------------------
// Fused convert+transpose for weights. in: f32 R x C -> out: bf16 C x R.
// grid.x = C/64, grid.y = R/64.
__global__ __launch_bounds__(256) void cvt_transpose_k(
    const float* __restrict__ in, unsigned short* __restrict__ out,
    int inStride, int outStride)
{
    __shared__ unsigned short tile[64][65];
    const int ti = blockIdx.x * 64;   // C dim (out row)
    const int tj = blockIdx.y * 64;   // R dim
    const int t = threadIdx.x;
    const int r = t >> 4;             // 0..15
    const int c4 = (t & 15) << 2;     // 0..60
#pragma unroll
    for (int i = 0; i < 4; ++i) {
        const float4 v = *(const float4*)(in + (size_t)(tj + r + i * 16) * inStride + ti + c4);
        tile[r + i * 16][c4 + 0] = f2bs(v.x);
        tile[r + i * 16][c4 + 1] = f2bs(v.y);
        tile[r + i * 16][c4 + 2] = f2bs(v.z);
        tile[r + i * 16][c4 + 3] = f2bs(v.w);
    }
    __syncthreads();
#pragma unroll
    for (int i = 0; i < 4; ++i) {
        const int orow = ti + r + i * 16;
        us4 v;
        v[0] = tile[c4 + 0][r + i * 16];
        v[1] = tile[c4 + 1][r + i * 16];
        v[2] = tile[c4 + 2][r + i * 16];
        v[3] = tile[c4 + 3][r + i * 16];
        *(us4*)(out + (size_t)orow * outStride + tj + c4) = v;
    }
}

// ---------------------------------------------------------------------------
// bf16 tiled transpose (for per-head value slices). in: R x C -> out: C x R.
// grid.z = slices (b,h): offset (z>>4)*inOffB + (z&15)*inOffH.
__global__ __launch_bounds__(256) void transpose_k(
    const unsigned short* __restrict__ in, unsigned short* __restrict__ out,
    int inStride, int outStride, size_t inOffB, int inOffH, size_t outSliceStride)
{
    __shared__ unsigned short tile[64][65];
    const int z = blockIdx.z;
    const unsigned short* inp = in + (size_t)(z >> 4) * inOffB + (size_t)(z & 15) * inOffH;
    unsigned short* outp = out + (size_t)z * outSliceStride;
    const int ti = blockIdx.x * 64;
    const int tj = blockIdx.y * 64;
    const int t = threadIdx.x;
    const int r = t >> 4;
    const int c4 = (t & 15) << 2;
#pragma unroll
    for (int i = 0; i < 4; ++i) {
        us4 v = *(const us4*)(inp + (size_t)(tj + r + i * 16) * inStride + ti + c4);
        tile[r + i * 16][c4 + 0] = v[0];
        tile[r + i * 16][c4 + 1] = v[1];
        tile[r + i * 16][c4 + 2] = v[2];
        tile[r + i * 16][c4 + 3] = v[3];
    }
    __syncthreads();
#pragma unroll
    for (int i = 0; i < 4; ++i) {
        const int orow = ti + r + i * 16;
        us4 v;
        v[0] = tile[c4 + 0][r + i * 16];
        v[1] = tile[c4 + 1][r + i * 16];
        v[2] = tile[c4 + 2][r + i * 16];
        v[3] = tile[c4 + 3][r + i * 16];
        *(us4*)(outp + (size_t)orow * outStride + tj + c4) = v;
    }
}

// ---------------------------------------------------------------------------
// C = relu(A @ B + bias) [* mask[row]], A bf16, BT bf16 (B transposed: BT[n][k]),
// bias/mask f32, OutT output. m97 recipe: 128x128 tile, BK=32, 4 waves 2x2.
template <typename OutT>
__global__ __launch_bounds__(256) void gemm_bt(
    const bf16* __restrict__ A, const bf16* __restrict__ BT,
    const float* __restrict__ bias, const float* __restrict__ mask,
    OutT* __restrict__ C, int K, int lda, int ldb, int ldc)
{
    __shared__ __align__(16) bf16 As[128 * 32];
    __shared__ __align__(16) bf16 Bs[128 * 32];
    const int tid = threadIdx.x;
    const int lane = tid & 63;
    const int l16 = lane & 15;
    const int quad = lane >> 4;
    const int wave = tid >> 6;
    const int wr = (wave >> 1) * 64;
    const int wc = (wave & 1) * 64;
    const size_t row0 = (size_t)blockIdx.y * 128;
    const size_t col0 = (size_t)blockIdx.x * 128;

    const f32x4 z4 = {0.f, 0.f, 0.f, 0.f};
    f32x4 acc[4][4];
#pragma unroll
    for (int r = 0; r < 4; ++r)
#pragma unroll
        for (int c = 0; c < 4; ++c) acc[r][c] = z4;

    const int e1 = tid * 8;
    const int m1 = e1 >> 5, k1 = e1 & 31;
    const int e2 = e1 + 2048;
    const int m2 = e2 >> 5, k2 = e2 & 31;

    for (int k0 = 0; k0 < K; k0 += 32) {
        gl_lds16(A  + (row0 + m1) * lda + k0 + k1, As + e1);
        gl_lds16(A  + (row0 + m2) * lda + k0 + k2, As + e2);
        gl_lds16(BT + (col0 + m1) * ldb + k0 + k1, Bs + e1);
        gl_lds16(BT + (col0 + m2) * ldb + k0 + k2, Bs + e2);
        __syncthreads();
        bf16x8 af[4], bfv[4];
#pragma unroll
        for (int r = 0; r < 4; ++r)
            af[r] = ld8(As + (wr + r * 16 + l16) * 32 + quad * 8);
#pragma unroll
        for (int c = 0; c < 4; ++c)
            bfv[c] = ld8(Bs + (wc + c * 16 + l16) * 32 + quad * 8);
#pragma unroll
        for (int r = 0; r < 4; ++r)
#pragma unroll
            for (int c = 0; c < 4; ++c)
                acc[r][c] = mfma16(af[r], bfv[c], acc[r][c]);
        __syncthreads();
    }

    // epilogue: D row = quad*4+reg, col = l16 (m89-verified C/D layout)
#pragma unroll
    for (int c = 0; c < 4; ++c) {
        const size_t col = col0 + wc + c * 16 + l16;
        const float bc = bias[col];
#pragma unroll
        for (int r = 0; r < 4; ++r) {
            const size_t rowb = row0 + wr + r * 16 + quad * 4;
#pragma unroll
            for (int g = 0; g < 4; ++g) {
                const size_t row = rowb + g;
                float v = acc[r][c][g] + bc;
                v = v > 0.f ? v : 0.f;
                if (mask) v *= mask[row];
                stout(&C[row * ldc + col], v);
            }
        }
    }
}

// ---------------------------------------------------------------------------
// Cross attention, one direction. grid.x = Lq/32, grid.y = B*H. 128 thr = 2 waves,
// each wave owns 16 query rows. S in registers (16 x 512 per wave), softmax via
// 16-lane shuffle reduce, P round-trips LDS (C-layout -> A-layout).
__global__ __launch_bounds__(128) void attn_k(
    const bf16* __restrict__ Q, const bf16* __restrict__ Kk,
    const bf16* __restrict__ VT, const float* __restrict__ kmask,
    bf16* __restrict__ Out,
    int Lq, int Lk, int qStride, int kStride, int outStride, int outColOff)
{
    const int bh = blockIdx.y;
    const int b = bh >> 4, h = bh & 15;
    const int n0 = blockIdx.x * 32;
    const int tid = threadIdx.x;
    const int wave = tid >> 6, lane = tid & 63;
    const int l16 = lane & 15, quad = lane >> 4;

    __shared__ __align__(16) bf16 Qs[32 * 128];
    __shared__ __align__(16) bf16 Ps[2][16 * 520];  // stride 520: 16B-aligned, conflict-free b128

    // stage Q tile (32 rows x 128 d)
#pragma unroll
    for (int i = 0; i < 4; ++i) {
        const int e = i * 1024 + tid * 8;
        const int r = e >> 7, d = e & 127;
        gl_lds16(Q + (size_t)(b * Lq + n0 + r) * qStride + h * 128 + d, Qs + e);
    }
    __syncthreads();

    bf16x8 aq[4];
#pragma unroll
    for (int ks = 0; ks < 4; ++ks)
        aq[ks] = ld8(Qs + (wave * 16 + l16) * 128 + ks * 32 + quad * 8);

    // QK^T: B-frag (K rows) straight from global, contiguous-k
    const bf16* Kg = Kk + (size_t)b * Lk * kStride + (size_t)l16 * kStride + h * 128 + quad * 8;
    f32x4 S[32];
#pragma unroll
    for (int t = 0; t < 32; ++t) {
        const bf16* kp = Kg + (size_t)t * 16 * kStride;
        f32x4 c = {0.f, 0.f, 0.f, 0.f};
        c = mfma16(aq[0], ld8(kp), c);
        c = mfma16(aq[1], ld8(kp + 32), c);
        c = mfma16(aq[2], ld8(kp + 64), c);
        c = mfma16(aq[3], ld8(kp + 96), c);
        S[t] = c;
    }

    const float scale = 0.08838834764831845f;  // 1/sqrt(128)
    float mx[4] = {-3.0e38f, -3.0e38f, -3.0e38f, -3.0e38f};
#pragma unroll
    for (int t = 0; t < 32; ++t)
#pragma unroll
        for (int g = 0; g < 4; ++g) mx[g] = fmaxf(mx[g], S[t][g]);
#pragma unroll
    for (int off = 1; off < 16; off <<= 1)
#pragma unroll
        for (int g = 0; g < 4; ++g) mx[g] = fmaxf(mx[g], __shfl_xor(mx[g], off));

    float sm[4] = {0.f, 0.f, 0.f, 0.f};
    const float* mrow = kmask + (size_t)b * Lk;
#pragma unroll
    for (int t = 0; t < 32; ++t) {
        const float mv = mrow[t * 16 + l16];
#pragma unroll
        for (int g = 0; g < 4; ++g) {
            float p = (mv != 0.f) ? __expf((S[t][g] - mx[g]) * scale) : 0.f;
            S[t][g] = p;
            sm[g] += p;
        }
    }
#pragma unroll
    for (int off = 1; off < 16; off <<= 1)
#pragma unroll
        for (int g = 0; g < 4; ++g) sm[g] += __shfl_xor(sm[g], off);
    float rs[4];
#pragma unroll
    for (int g = 0; g < 4; ++g) rs[g] = 1.f / sm[g];

    // P: C-layout regs -> LDS [row16][520]
    bf16* pw = Ps[wave];
#pragma unroll
    for (int t = 0; t < 32; ++t) {
        const int col = t * 16 + l16;
#pragma unroll
        for (int g = 0; g < 4; ++g)
            pw[(quad * 4 + g) * 520 + col] = __float2bfloat16(S[t][g] * rs[g]);
    }
    // order the scalar P-stores before the vector P-loads (TBAA differs)
    asm volatile("" ::: "memory");
    __syncthreads();

    bf16x8 pa[16];
#pragma unroll
    for (int ks = 0; ks < 16; ++ks)
        pa[ks] = ld8(pw + l16 * 520 + ks * 32 + quad * 8);

    // PV: B-frag from pre-transposed V^T [bh][d][m], contiguous-m
    const bf16* Vg = VT + (size_t)bh * 128 * Lk + (size_t)l16 * Lk + quad * 8;
    const size_t orow = (size_t)b * Lq + n0 + wave * 16 + quad * 4;
#pragma unroll
    for (int dt = 0; dt < 8; ++dt) {
        const bf16* vp = Vg + (size_t)dt * 16 * Lk;
        f32x4 c = {0.f, 0.f, 0.f, 0.f};
#pragma unroll
        for (int ks = 0; ks < 16; ++ks)
            c = mfma16(pa[ks], ld8(vp + ks * 32), c);
        const int col = outColOff + h * 128 + dt * 16 + l16;
#pragma unroll
        for (int g = 0; g < 4; ++g)
            Out[(orow + g) * outStride + col] = __float2bfloat16(c[g]);
    }
}

// ---------------------------------------------------------------------------
extern "C" void kernel_launch(void* const* d_in, const int* in_sizes, int n_in,
                              void* d_out, int out_size, void* d_ws, size_t ws_size,
                              hipStream_t stream)
{
    (void)in_sizes; (void)n_in; (void)out_size; (void)ws_size;
    const float* v   = (const float*)d_in[0];
    const float* q   = (const float*)d_in[1];
    const float* vm  = (const float*)d_in[2];
    const float* qm  = (const float*)d_in[3];
    const float* Wv  = (const float*)d_in[4];
    const float* bv  = (const float*)d_in[5];
    const float* Wq  = (const float*)d_in[6];
    const float* bq  = (const float*)d_in[7];
    const float* Wvo = (const float*)d_in[8];
    const float* bvo = (const float*)d_in[9];
    const float* Wqo = (const float*)d_in[10];
    const float* bqo = (const float*)d_in[11];

    float* out_v = (float*)d_out;
    float* out_q = out_v + (size_t)8192 * 2048;

    bf16* ws = (bf16*)d_ws;
    bf16* v_trans = ws; ws += (size_t)8192 * 6144;
    bf16* q_trans = ws; ws += (size_t)8192 * 6144;
    bf16* vcat    = ws; ws += (size_t)8192 * 4096;   // [v(bf16) | v_update]
    bf16* qcat    = ws; ws += (size_t)8192 * 3072;   // [q(bf16) | q_update]
    bf16* WvT     = ws; ws += (size_t)6144 * 2048;
    bf16* WqT     = ws; ws += (size_t)6144 * 1024;
    bf16* WvoT    = ws; ws += (size_t)2048 * 4096;
    bf16* WqoT    = ws; ws += (size_t)2048 * 3072;
    bf16* VvalT   = ws; ws += (size_t)256 * 128 * 512;
    bf16* QvalT   = ws; ws += (size_t)256 * 128 * 512;
    // 226,492,416 bf16 elems = 432 MiB of d_ws

    // 1) convert inputs to bf16 into concat-left (also the GEMM A operands)
    cvt_cols_k<<<8192, 256, 0, stream>>>(v, vcat, 8, 4096, 8192 * 256);
    cvt_cols_k<<<4096, 256, 0, stream>>>(q, qcat, 7, 3072, 8192 * 128);

    // 2) weight convert+transpose (f32 R x C -> bf16 C x R)
    cvt_transpose_k<<<dim3(96, 32), 256, 0, stream>>>(Wv,  (unsigned short*)WvT,  6144, 2048);
    cvt_transpose_k<<<dim3(96, 16), 256, 0, stream>>>(Wq,  (unsigned short*)WqT,  6144, 1024);
    cvt_transpose_k<<<dim3(32, 64), 256, 0, stream>>>(Wvo, (unsigned short*)WvoT, 2048, 4096);
    cvt_transpose_k<<<dim3(32, 48), 256, 0, stream>>>(Wqo, (unsigned short*)WqoT, 2048, 3072);

    // 3) input projections (A = concat-left, wider lda)
    gemm_bt<bf16><<<dim3(48, 64), 256, 0, stream>>>(vcat, WvT, bv, vm, v_trans, 2048, 4096, 2048, 6144);
    gemm_bt<bf16><<<dim3(48, 64), 256, 0, stream>>>(qcat, WqT, bq, qm, q_trans, 1024, 3072, 1024, 6144);

    // 4) value-slice transposes: [b,n,h,d] -> [bh][d][n]
    transpose_k<<<dim3(2, 8, 256), 256, 0, stream>>>((const unsigned short*)(v_trans + 4096), (unsigned short*)VvalT,
                                                     6144, 512, (size_t)512 * 6144, 128, 65536);
    transpose_k<<<dim3(2, 8, 256), 256, 0, stream>>>((const unsigned short*)(q_trans + 4096), (unsigned short*)QvalT,
                                                     6144, 512, (size_t)512 * 6144, 128, 65536);

    // 5) cross attention: q2v (v_qry x q_key -> v_update), v2q (q_qry x v_key -> q_update)
    attn_k<<<dim3(16, 256), 128, 0, stream>>>(v_trans + 2048, q_trans, QvalT, qm, vcat,
                                              512, 512, 6144, 6144, 4096, 2048);
    attn_k<<<dim3(16, 256), 128, 0, stream>>>(q_trans + 2048, v_trans, VvalT, vm, qcat,
                                              512, 512, 6144, 6144, 3072, 1024);

    // 6) output projections -> d_out (f32 stores)
    gemm_bt<float><<<dim3(16, 64), 256, 0, stream>>>(vcat, WvoT, bvo, nullptr, out_v, 4096, 4096, 4096, 2048);
    gemm_bt<float><<<dim3(16, 64), 256, 0, stream>>>(qcat, WqoT, bqo, nullptr, out_q, 3072, 3072, 3072, 2048);
}

// Round 4
// 1787.978 us; speedup vs baseline: 1.0027x; 1.0027x over previous
//
#include <hip/hip_runtime.h>
#include <hip/hip_bf16.h>
#include <cstdint>

// InterModalityUpdate — f32 in/out, bf16 MFMA internally (fp32 accum).
// R4: LDS-staged coalesced GEMM epilogue (fixes partial-dirty-line eviction:
//     WRITE_SIZE was 2x ideal, FETCH +100MB RFO); attn Qs/Ps LDS union (3->4 blocks/CU).
// Dims fixed: B=16 N=M=512 VS=2048 QS=1024 OS=2048 H=16 DH=128.

typedef __hip_bfloat16 bf16;
typedef __attribute__((ext_vector_type(8))) __bf16 bf16x8;
typedef __attribute__((ext_vector_type(4))) float f32x4;
typedef __attribute__((ext_vector_type(4))) unsigned short us4;
typedef __attribute__((ext_vector_type(8))) unsigned short us8;

#define AS1 __attribute__((address_space(1)))
#define AS3 __attribute__((address_space(3)))

__device__ __forceinline__ void gl_lds16(const bf16* g, bf16* l) {
    __builtin_amdgcn_global_load_lds((AS1 void*)(uintptr_t)(g), (AS3 void*)(l), 16, 0, 0);
}

__device__ __forceinline__ bf16x8 ld8(const bf16* p) { return *(const bf16x8*)p; }

__device__ __forceinline__ f32x4 mfma16(bf16x8 a, bf16x8 b, f32x4 c) {
    return __builtin_amdgcn_mfma_f32_16x16x32_bf16(a, b, c, 0, 0, 0);
}

// f32 -> bf16 bits, round-to-nearest-even (finite inputs)
__device__ __forceinline__ unsigned short f2bs(float f) {
    unsigned u = __builtin_bit_cast(unsigned, f);
    unsigned r = u + 0x7FFFu + ((u >> 16) & 1u);
    return (unsigned short)(r >> 16);
}

// ---------------------------------------------------------------------------
// f32 -> bf16 convert into left columns of a wider bf16 matrix. 8 elems/thread.
__global__ __launch_bounds__(256) void cvt_cols_k(
    const float* __restrict__ src, bf16* __restrict__ dst,
    int cprShift, int dstStride, int totalChunks)
{
    const int id = blockIdx.x * 256 + threadIdx.x;
    if (id >= totalChunks) return;
    const int row = id >> cprShift;
    const int cc = (id - (row << cprShift)) << 3;
    const float* s = src + ((size_t)row << (cprShift + 3)) + cc;
    const float4 a = *(const float4*)s;
    const float4 b = *(const float4*)(s + 4);
    us8 o;
    o[0] = f2bs(a.x); o[1] = f2bs(a.y); o[2] = f2bs(a.z); o[3] = f2bs(a.w);
    o[4] = f2bs(b.x); o[5] = f2bs(b.y); o[6] = f2bs(b.z); o[7] = f2bs(b.w);
    *(us8*)(dst + (size_t)row * dstStride + cc) = o;
}

// ---------------------------------------------------------------------------
// Fused convert+transpose for weights. f32 R x C -> bf16 C x R.
__global__ __launch_bounds__(256) void cvt_transpose_k(
    const float* __restrict__ in, unsigned short* __restrict__ out,
    int inStride, int outStride)
{
    __shared__ unsigned short tile[64][65];
    const int ti = blockIdx.x * 64;
    const int tj = blockIdx.y * 64;
    const int t = threadIdx.x;
    const int r = t >> 4;
    const int c4 = (t & 15) << 2;
#pragma unroll
    for (int i = 0; i < 4; ++i) {
        const float4 v = *(const float4*)(in + (size_t)(tj + r + i * 16) * inStride + ti + c4);
        tile[r + i * 16][c4 + 0] = f2bs(v.x);
        tile[r + i * 16][c4 + 1] = f2bs(v.y);
        tile[r + i * 16][c4 + 2] = f2bs(v.z);
        tile[r + i * 16][c4 + 3] = f2bs(v.w);
    }
    __syncthreads();
#pragma unroll
    for (int i = 0; i < 4; ++i) {
        const int orow = ti + r + i * 16;
        us4 v;
        v[0] = tile[c4 + 0][r + i * 16];
        v[1] = tile[c4 + 1][r + i * 16];
        v[2] = tile[c4 + 2][r + i * 16];
        v[3] = tile[c4 + 3][r + i * 16];
        *(us4*)(out + (size_t)orow * outStride + tj + c4) = v;
    }
}

// ---------------------------------------------------------------------------
// bf16 tiled transpose (per-head value slices). grid.z slice offset:
// (z>>4)*inOffB + (z&15)*inOffH.
__global__ __launch_bounds__(256) void transpose_k(
    const unsigned short* __restrict__ in, unsigned short* __restrict__ out,
    int inStride, int outStride, size_t inOffB, int inOffH, size_t outSliceStride)
{
    __shared__ unsigned short tile[64][65];
    const int z = blockIdx.z;
    const unsigned short* inp = in + (size_t)(z >> 4) * inOffB + (size_t)(z & 15) * inOffH;
    unsigned short* outp = out + (size_t)z * outSliceStride;
    const int ti = blockIdx.x * 64;
    const int tj = blockIdx.y * 64;
    const int t = threadIdx.x;
    const int r = t >> 4;
    const int c4 = (t & 15) << 2;
#pragma unroll
    for (int i = 0; i < 4; ++i) {
        us4 v = *(const us4*)(inp + (size_t)(tj + r + i * 16) * inStride + ti + c4);
        tile[r + i * 16][c4 + 0] = v[0];
        tile[r + i * 16][c4 + 1] = v[1];
        tile[r + i * 16][c4 + 2] = v[2];
        tile[r + i * 16][c4 + 3] = v[3];
    }
    __syncthreads();
#pragma unroll
    for (int i = 0; i < 4; ++i) {
        const int orow = ti + r + i * 16;
        us4 v;
        v[0] = tile[c4 + 0][r + i * 16];
        v[1] = tile[c4 + 1][r + i * 16];
        v[2] = tile[c4 + 2][r + i * 16];
        v[3] = tile[c4 + 3][r + i * 16];
        *(us4*)(outp + (size_t)orow * outStride + tj + c4) = v;
    }
}

// ---------------------------------------------------------------------------
// C = relu(A @ B + bias) [* mask[row]]; BT[n][k]. 128x128 tile, BK=32, 4 waves.
// Epilogue staged through LDS for linear, line-complete global stores.
template <typename OutT>
__global__ __launch_bounds__(256) void gemm_bt(
    const bf16* __restrict__ A, const bf16* __restrict__ BT,
    const float* __restrict__ bias, const float* __restrict__ mask,
    OutT* __restrict__ C, int K, int lda, int ldb, int ldc)
{
    __shared__ __align__(16) bf16 smem[8192];   // As | Bs; reused as epilogue staging
    bf16* As = smem;
    bf16* Bs = smem + 4096;
    const int tid = threadIdx.x;
    const int lane = tid & 63;
    const int l16 = lane & 15;
    const int quad = lane >> 4;
    const int wave = tid >> 6;
    const int wr = (wave >> 1) * 64;
    const int wc = (wave & 1) * 64;
    const size_t row0 = (size_t)blockIdx.y * 128;
    const size_t col0 = (size_t)blockIdx.x * 128;

    const f32x4 z4 = {0.f, 0.f, 0.f, 0.f};
    f32x4 acc[4][4];
#pragma unroll
    for (int r = 0; r < 4; ++r)
#pragma unroll
        for (int c = 0; c < 4; ++c) acc[r][c] = z4;

    const int e1 = tid * 8;
    const int m1 = e1 >> 5, k1 = e1 & 31;
    const int e2 = e1 + 2048;
    const int m2 = e2 >> 5, k2 = e2 & 31;

    for (int k0 = 0; k0 < K; k0 += 32) {
        gl_lds16(A  + (row0 + m1) * lda + k0 + k1, As + e1);
        gl_lds16(A  + (row0 + m2) * lda + k0 + k2, As + e2);
        gl_lds16(BT + (col0 + m1) * ldb + k0 + k1, Bs + e1);
        gl_lds16(BT + (col0 + m2) * ldb + k0 + k2, Bs + e2);
        __syncthreads();
        bf16x8 af[4], bfv[4];
#pragma unroll
        for (int r = 0; r < 4; ++r)
            af[r] = ld8(As + (wr + r * 16 + l16) * 32 + quad * 8);
#pragma unroll
        for (int c = 0; c < 4; ++c)
            bfv[c] = ld8(Bs + (wc + c * 16 + l16) * 32 + quad * 8);
#pragma unroll
        for (int r = 0; r < 4; ++r)
#pragma unroll
            for (int c = 0; c < 4; ++c)
                acc[r][c] = mfma16(af[r], bfv[c], acc[r][c]);
        __syncthreads();
    }

    // fragment value (bias+relu+mask), D row = quad*4+reg, col = l16
    float bcol[4];
#pragma unroll
    for (int c = 0; c < 4; ++c) bcol[c] = bias[col0 + wc + c * 16 + l16];

    if constexpr (sizeof(OutT) == 2) {
        // bf16 out: 4 passes x 32 rows; staging stride 136 (bank-friendly)
        bf16* stg = smem;
#pragma unroll
        for (int p = 0; p < 4; ++p) {
            if (wr == (p >> 1) * 64) {
#pragma unroll
                for (int rr = 0; rr < 2; ++rr) {
                    const int r = (p & 1) * 2 + rr;
#pragma unroll
                    for (int c = 0; c < 4; ++c) {
                        const int lcol = wc + c * 16 + l16;
#pragma unroll
                        for (int g = 0; g < 4; ++g) {
                            const int lrow = rr * 16 + quad * 4 + g;
                            const size_t grow = row0 + wr + r * 16 + quad * 4 + g;
                            float v = acc[r][c][g] + bcol[c];
                            v = v > 0.f ? v : 0.f;
                            if (mask) v *= mask[grow];
                            ((unsigned short*)stg)[lrow * 136 + lcol] = f2bs(v);
                        }
                    }
                }
            }
            asm volatile("" ::: "memory");
            __syncthreads();
            const int srow = tid >> 3;            // 0..31
            const int scol = (tid & 7) * 16;      // 0..112
            const us8 o0 = *(const us8*)((unsigned short*)stg + srow * 136 + scol);
            const us8 o1 = *(const us8*)((unsigned short*)stg + srow * 136 + scol + 8);
            OutT* dst = C + (row0 + p * 32 + srow) * ldc + col0 + scol;
            *(us8*)dst = o0;
            *(us8*)(dst + 8) = o1;
            __syncthreads();
        }
    } else {
        // f32 out: 8 passes x 16 rows; staging stride 132 f32
        float* stg = (float*)smem;
#pragma unroll
        for (int p = 0; p < 8; ++p) {
            if (wr == (p >> 2) * 64) {
                const int r = p & 3;
#pragma unroll
                for (int c = 0; c < 4; ++c) {
                    const int lcol = wc + c * 16 + l16;
#pragma unroll
                    for (int g = 0; g < 4; ++g) {
                        const int lrow = quad * 4 + g;
                        const size_t grow = row0 + wr + r * 16 + quad * 4 + g;
                        float v = acc[r][c][g] + bcol[c];
                        v = v > 0.f ? v : 0.f;
                        if (mask) v *= mask[grow];
                        stg[lrow * 132 + lcol] = v;
                    }
                }
            }
            asm volatile("" ::: "memory");
            __syncthreads();
            const int srow = tid >> 4;            // 0..15
            const int scol = (tid & 15) * 8;      // 0..120
            const f32x4 o0 = *(const f32x4*)(stg + srow * 132 + scol);
            const f32x4 o1 = *(const f32x4*)(stg + srow * 132 + scol + 4);
            OutT* dst = C + (row0 + p * 16 + srow) * ldc + col0 + scol;
            *(f32x4*)dst = o0;
            *(f32x4*)(dst + 4) = o1;
            __syncthreads();
        }
    }
}

// ---------------------------------------------------------------------------
// Cross attention. grid.x = Lq/32, grid.y = B*H. 128 thr = 2 waves x 16 q-rows.
// S in registers (16x512/wave), softmax via 16-lane shuffle reduce,
// P LDS round-trip (C-layout -> A-layout). Qs/Ps share one LDS buffer.
__global__ __launch_bounds__(128) void attn_k(
    const bf16* __restrict__ Q, const bf16* __restrict__ Kk,
    const bf16* __restrict__ VT, const float* __restrict__ kmask,
    bf16* __restrict__ Out,
    int Lq, int Lk, int qStride, int kStride, int outStride, int outColOff)
{
    const int bh = blockIdx.y;
    const int b = bh >> 4, h = bh & 15;
    const int n0 = blockIdx.x * 32;
    const int tid = threadIdx.x;
    const int wave = tid >> 6, lane = tid & 63;
    const int l16 = lane & 15, quad = lane >> 4;

    __shared__ __align__(16) bf16 smem[16640];  // Qs(32x128) then Ps[2][16x520]

    // stage Q tile (32 rows x 128 d)
#pragma unroll
    for (int i = 0; i < 4; ++i) {
        const int e = i * 1024 + tid * 8;
        const int r = e >> 7, d = e & 127;
        gl_lds16(Q + (size_t)(b * Lq + n0 + r) * qStride + h * 128 + d, smem + e);
    }
    __syncthreads();

    bf16x8 aq[4];
#pragma unroll
    for (int ks = 0; ks < 4; ++ks)
        aq[ks] = ld8(smem + (wave * 16 + l16) * 128 + ks * 32 + quad * 8);
    __syncthreads();   // union: both waves done reading Qs before Ps overwrites

    // QK^T: B-frag (K rows) straight from global, contiguous-k
    const bf16* Kg = Kk + (size_t)b * Lk * kStride + (size_t)l16 * kStride + h * 128 + quad * 8;
    f32x4 S[32];
#pragma unroll
    for (int t = 0; t < 32; ++t) {
        const bf16* kp = Kg + (size_t)t * 16 * kStride;
        f32x4 c = {0.f, 0.f, 0.f, 0.f};
        c = mfma16(aq[0], ld8(kp), c);
        c = mfma16(aq[1], ld8(kp + 32), c);
        c = mfma16(aq[2], ld8(kp + 64), c);
        c = mfma16(aq[3], ld8(kp + 96), c);
        S[t] = c;
    }

    const float scale = 0.08838834764831845f;  // 1/sqrt(128)
    float mx[4] = {-3.0e38f, -3.0e38f, -3.0e38f, -3.0e38f};
#pragma unroll
    for (int t = 0; t < 32; ++t)
#pragma unroll
        for (int g = 0; g < 4; ++g) mx[g] = fmaxf(mx[g], S[t][g]);
#pragma unroll
    for (int off = 1; off < 16; off <<= 1)
#pragma unroll
        for (int g = 0; g < 4; ++g) mx[g] = fmaxf(mx[g], __shfl_xor(mx[g], off));

    float sm[4] = {0.f, 0.f, 0.f, 0.f};
    const float* mrow = kmask + (size_t)b * Lk;
#pragma unroll
    for (int t = 0; t < 32; ++t) {
        const float mv = mrow[t * 16 + l16];
#pragma unroll
        for (int g = 0; g < 4; ++g) {
            float p = (mv != 0.f) ? __expf((S[t][g] - mx[g]) * scale) : 0.f;
            S[t][g] = p;
            sm[g] += p;
        }
    }
#pragma unroll
    for (int off = 1; off < 16; off <<= 1)
#pragma unroll
        for (int g = 0; g < 4; ++g) sm[g] += __shfl_xor(sm[g], off);
    float rs[4];
#pragma unroll
    for (int g = 0; g < 4; ++g) rs[g] = 1.f / sm[g];

    // P: C-layout regs -> LDS [row16][520]
    bf16* pw = smem + wave * 8320;
#pragma unroll
    for (int t = 0; t < 32; ++t) {
        const int col = t * 16 + l16;
#pragma unroll
        for (int g = 0; g < 4; ++g)
            pw[(quad * 4 + g) * 520 + col] = __float2bfloat16(S[t][g] * rs[g]);
    }
    asm volatile("" ::: "memory");
    __syncthreads();

    bf16x8 pa[16];
#pragma unroll
    for (int ks = 0; ks < 16; ++ks)
        pa[ks] = ld8(pw + l16 * 520 + ks * 32 + quad * 8);

    // PV: B-frag from pre-transposed V^T [bh][d][m], contiguous-m
    const bf16* Vg = VT + (size_t)bh * 128 * Lk + (size_t)l16 * Lk + quad * 8;
    const size_t orow = (size_t)b * Lq + n0 + wave * 16 + quad * 4;
#pragma unroll
    for (int dt = 0; dt < 8; ++dt) {
        const bf16* vp = Vg + (size_t)dt * 16 * Lk;
        f32x4 c = {0.f, 0.f, 0.f, 0.f};
#pragma unroll
        for (int ks = 0; ks < 16; ++ks)
            c = mfma16(pa[ks], ld8(vp + ks * 32), c);
        const int col = outColOff + h * 128 + dt * 16 + l16;
#pragma unroll
        for (int g = 0; g < 4; ++g)
            Out[(orow + g) * outStride + col] = __float2bfloat16(c[g]);
    }
}

// ---------------------------------------------------------------------------
extern "C" void kernel_launch(void* const* d_in, const int* in_sizes, int n_in,
                              void* d_out, int out_size, void* d_ws, size_t ws_size,
                              hipStream_t stream)
{
    (void)in_sizes; (void)n_in; (void)out_size; (void)ws_size;
    const float* v   = (const float*)d_in[0];
    const float* q   = (const float*)d_in[1];
    const float* vm  = (const float*)d_in[2];
    const float* qm  = (const float*)d_in[3];
    const float* Wv  = (const float*)d_in[4];
    const float* bv  = (const float*)d_in[5];
    const float* Wq  = (const float*)d_in[6];
    const float* bq  = (const float*)d_in[7];
    const float* Wvo = (const float*)d_in[8];
    const float* bvo = (const float*)d_in[9];
    const float* Wqo = (const float*)d_in[10];
    const float* bqo = (const float*)d_in[11];

    float* out_v = (float*)d_out;
    float* out_q = out_v + (size_t)8192 * 2048;

    bf16* ws = (bf16*)d_ws;
    bf16* v_trans = ws; ws += (size_t)8192 * 6144;
    bf16* q_trans = ws; ws += (size_t)8192 * 6144;
    bf16* vcat    = ws; ws += (size_t)8192 * 4096;   // [v(bf16) | v_update]
    bf16* qcat    = ws; ws += (size_t)8192 * 3072;   // [q(bf16) | q_update]
    bf16* WvT     = ws; ws += (size_t)6144 * 2048;
    bf16* WqT     = ws; ws += (size_t)6144 * 1024;
    bf16* WvoT    = ws; ws += (size_t)2048 * 4096;
    bf16* WqoT    = ws; ws += (size_t)2048 * 3072;
    bf16* VvalT   = ws; ws += (size_t)256 * 128 * 512;
    bf16* QvalT   = ws; ws += (size_t)256 * 128 * 512;
    // 432 MiB of d_ws

    // 1) convert inputs to bf16 into concat-left (also the GEMM A operands)
    cvt_cols_k<<<8192, 256, 0, stream>>>(v, vcat, 8, 4096, 8192 * 256);
    cvt_cols_k<<<4096, 256, 0, stream>>>(q, qcat, 7, 3072, 8192 * 128);

    // 2) weight convert+transpose (f32 R x C -> bf16 C x R)
    cvt_transpose_k<<<dim3(96, 32), 256, 0, stream>>>(Wv,  (unsigned short*)WvT,  6144, 2048);
    cvt_transpose_k<<<dim3(96, 16), 256, 0, stream>>>(Wq,  (unsigned short*)WqT,  6144, 1024);
    cvt_transpose_k<<<dim3(32, 64), 256, 0, stream>>>(Wvo, (unsigned short*)WvoT, 2048, 4096);
    cvt_transpose_k<<<dim3(32, 48), 256, 0, stream>>>(Wqo, (unsigned short*)WqoT, 2048, 3072);

    // 3) input projections
    gemm_bt<bf16><<<dim3(48, 64), 256, 0, stream>>>(vcat, WvT, bv, vm, v_trans, 2048, 4096, 2048, 6144);
    gemm_bt<bf16><<<dim3(48, 64), 256, 0, stream>>>(qcat, WqT, bq, qm, q_trans, 1024, 3072, 1024, 6144);

    // 4) value-slice transposes: [b,n,h,d] -> [bh][d][n]
    transpose_k<<<dim3(2, 8, 256), 256, 0, stream>>>((const unsigned short*)(v_trans + 4096), (unsigned short*)VvalT,
                                                     6144, 512, (size_t)512 * 6144, 128, 65536);
    transpose_k<<<dim3(2, 8, 256), 256, 0, stream>>>((const unsigned short*)(q_trans + 4096), (unsigned short*)QvalT,
                                                     6144, 512, (size_t)512 * 6144, 128, 65536);

    // 5) cross attention
    attn_k<<<dim3(16, 256), 128, 0, stream>>>(v_trans + 2048, q_trans, QvalT, qm, vcat,
                                              512, 512, 6144, 6144, 4096, 2048);
    attn_k<<<dim3(16, 256), 128, 0, stream>>>(q_trans + 2048, v_trans, VvalT, vm, qcat,
                                              512, 512, 6144, 6144, 3072, 1024);

    // 6) output projections -> d_out (f32, LDS-staged stores)
    gemm_bt<float><<<dim3(16, 64), 256, 0, stream>>>(vcat, WvoT, bvo, nullptr, out_v, 4096, 4096, 4096, 2048);
    gemm_bt<float><<<dim3(16, 64), 256, 0, stream>>>(qcat, WqoT, bqo, nullptr, out_q, 3072, 3072, 3072, 2048);
}